// Round 1
// baseline (121.369 us; speedup 1.0000x reference)
//
#include <hip/hip_runtime.h>
#include <hip/hip_bf16.h>
#include <math.h>

#define BSZ 512
#define KDIM 2048
#define UO 1024
#define JSPLIT 32
#define JCHUNK (BSZ / JSPLIT)  // 16

typedef __bf16 bf16x8 __attribute__((ext_vector_type(8)));
typedef float floatx4 __attribute__((ext_vector_type(4)));

__device__ __forceinline__ unsigned short f2bf(float f) {
    unsigned int u = __builtin_bit_cast(unsigned int, f);
    u += 0x7FFFu + ((u >> 16) & 1u);  // RNE
    return (unsigned short)(u >> 16);
}

// x [512][2048] fp32 -> bf16, elementwise. 1024 blocks x 256 thr x 4 elems.
__global__ void conv_x_kernel(const float* __restrict__ x, unsigned short* __restrict__ xb) {
    int t = blockIdx.x * 256 + threadIdx.x;
    float4 v = ((const float4*)x)[t];
    ushort4 o4;
    o4.x = f2bf(v.x); o4.y = f2bf(v.y); o4.z = f2bf(v.z); o4.w = f2bf(v.w);
    ((ushort4*)xb)[t] = o4;
}

// w [2048][1024] fp32 -> wt [1024][2048] bf16 (transposed), 32x32 tiles via LDS.
__global__ void conv_w_kernel(const float* __restrict__ w, unsigned short* __restrict__ wt) {
    __shared__ unsigned short tile[32][33];
    int n0 = blockIdx.x * 32, k0 = blockIdx.y * 32;
    int tx = threadIdx.x, ty = threadIdx.y;  // 32 x 8
#pragma unroll
    for (int s = 0; s < 4; ++s) {
        int kk = ty + 8 * s;
        tile[kk][tx] = f2bf(w[(k0 + kk) * 1024 + n0 + tx]);
    }
    __syncthreads();
#pragma unroll
    for (int s = 0; s < 4; ++s) {
        int r = ty + 8 * s;
        wt[(n0 + r) * 2048 + k0 + tx] = tile[tx][r];
    }
}

// h[m][n] = sum_k xb[m][k] * wt[n][k].  M=512, N=1024, K=2048, fp32 out.
// 64x64 block tile, 4 waves as 2x2 of 32x32 wave tiles, BK=32, mfma 16x16x32 bf16.
__global__ __launch_bounds__(256) void gemm_kernel(const unsigned short* __restrict__ xb,
                                                   const unsigned short* __restrict__ wt,
                                                   float* __restrict__ h) {
    __shared__ uint4 As4[64][4];  // [m][kquad] : 64 rows x 32 bf16
    __shared__ uint4 Bs4[64][4];  // [n][kquad]
    const int t = threadIdx.x;
    const int m0 = blockIdx.y * 64, n0 = blockIdx.x * 64;
    const int w = t >> 6, l = t & 63;
    const int wm = (w >> 1) * 32, wn = (w & 1) * 32;
    const int lf = l & 15, q = l >> 4;

    const int srow = t >> 2, skq = t & 3;
    const unsigned short* ga = xb + (m0 + srow) * 2048 + skq * 8;
    const unsigned short* gb = wt + (n0 + srow) * 2048 + skq * 8;

    floatx4 acc00 = {0.f,0.f,0.f,0.f}, acc01 = {0.f,0.f,0.f,0.f};
    floatx4 acc10 = {0.f,0.f,0.f,0.f}, acc11 = {0.f,0.f,0.f,0.f};

    for (int k0 = 0; k0 < KDIM; k0 += 32) {
        __syncthreads();
        As4[srow][skq] = *(const uint4*)(ga + k0);
        Bs4[srow][skq] = *(const uint4*)(gb + k0);
        __syncthreads();
        bf16x8 a0 = __builtin_bit_cast(bf16x8, As4[wm + 0  + lf][q]);
        bf16x8 a1 = __builtin_bit_cast(bf16x8, As4[wm + 16 + lf][q]);
        bf16x8 b0 = __builtin_bit_cast(bf16x8, Bs4[wn + 0  + lf][q]);
        bf16x8 b1 = __builtin_bit_cast(bf16x8, Bs4[wn + 16 + lf][q]);
        acc00 = __builtin_amdgcn_mfma_f32_16x16x32_bf16(a0, b0, acc00, 0, 0, 0);
        acc01 = __builtin_amdgcn_mfma_f32_16x16x32_bf16(a0, b1, acc01, 0, 0, 0);
        acc10 = __builtin_amdgcn_mfma_f32_16x16x32_bf16(a1, b0, acc10, 0, 0, 0);
        acc11 = __builtin_amdgcn_mfma_f32_16x16x32_bf16(a1, b1, acc11, 0, 0, 0);
    }
    // C/D: col = lane&15, row = quad*4 + reg
#pragma unroll
    for (int r = 0; r < 4; ++r) {
        int gm0 = m0 + wm + q * 4 + r;
        int gn0 = n0 + wn + lf;
        h[gm0 * 1024 + gn0]              = acc00[r];
        h[gm0 * 1024 + gn0 + 16]         = acc01[r];
        h[(gm0 + 16) * 1024 + gn0]       = acc10[r];
        h[(gm0 + 16) * 1024 + gn0 + 16]  = acc11[r];
    }
}

// features[i][o] = sum_j exp(-sum_u |h[i][u*32+o] - h[j][u*32+o]|)
// grid (JSPLIT, 16): block handles 32 i's x all o, j-chunk of 16.
// thread t: o = t&31, s = t>>5; 4 i's (ibase + s*4 + p) in registers (128 VGPR).
// h[j] staged per j into LDS as float4 buf[g*32+o] = h[j][(4g..4g+3)*32+o].
__global__ __launch_bounds__(256) void pairwise_kernel(const float* __restrict__ h,
                                                       float* __restrict__ part) {
    __shared__ float4 buf[2][256];
    const int t = threadIdx.x;
    const int o = t & 31, s = t >> 5;
    const int ibase = blockIdx.y * 32;
    const int j0 = blockIdx.x * JCHUNK;

    float hi[4][32];
#pragma unroll
    for (int p = 0; p < 4; ++p) {
        const float* hrow = h + (ibase + s * 4 + p) * 1024 + o;
#pragma unroll
        for (int u = 0; u < 32; ++u) hi[p][u] = hrow[u * 32];
    }

    // stage j0 (coalesced: 4 dword loads, one ds_write_b128)
    {
        const float* hj = h + j0 * 1024 + o;
        float4 v;
        v.x = hj[(4 * s + 0) * 32]; v.y = hj[(4 * s + 1) * 32];
        v.z = hj[(4 * s + 2) * 32]; v.w = hj[(4 * s + 3) * 32];
        buf[0][s * 32 + o] = v;
    }
    __syncthreads();

    float acc[4] = {0.f, 0.f, 0.f, 0.f};
    int cur = 0;
    for (int jj = 0; jj < JCHUNK; ++jj) {
        float4 nv;
        const bool has_next = (jj + 1 < JCHUNK);
        if (has_next) {
            const float* hj = h + (j0 + jj + 1) * 1024 + o;
            nv.x = hj[(4 * s + 0) * 32]; nv.y = hj[(4 * s + 1) * 32];
            nv.z = hj[(4 * s + 2) * 32]; nv.w = hj[(4 * s + 3) * 32];
        }
        float d0 = 0.f, d1 = 0.f, d2 = 0.f, d3 = 0.f;
#pragma unroll
        for (int g = 0; g < 8; ++g) {
            float4 hj4 = buf[cur][g * 32 + o];
            d0 += fabsf(hi[0][4*g+0] - hj4.x); d1 += fabsf(hi[1][4*g+0] - hj4.x);
            d2 += fabsf(hi[2][4*g+0] - hj4.x); d3 += fabsf(hi[3][4*g+0] - hj4.x);
            d0 += fabsf(hi[0][4*g+1] - hj4.y); d1 += fabsf(hi[1][4*g+1] - hj4.y);
            d2 += fabsf(hi[2][4*g+1] - hj4.y); d3 += fabsf(hi[3][4*g+1] - hj4.y);
            d0 += fabsf(hi[0][4*g+2] - hj4.z); d1 += fabsf(hi[1][4*g+2] - hj4.z);
            d2 += fabsf(hi[2][4*g+2] - hj4.z); d3 += fabsf(hi[3][4*g+2] - hj4.z);
            d0 += fabsf(hi[0][4*g+3] - hj4.w); d1 += fabsf(hi[1][4*g+3] - hj4.w);
            d2 += fabsf(hi[2][4*g+3] - hj4.w); d3 += fabsf(hi[3][4*g+3] - hj4.w);
        }
        acc[0] += __expf(-d0); acc[1] += __expf(-d1);
        acc[2] += __expf(-d2); acc[3] += __expf(-d3);
        if (has_next) buf[cur ^ 1][s * 32 + o] = nv;
        __syncthreads();
        cur ^= 1;
    }
#pragma unroll
    for (int p = 0; p < 4; ++p)
        part[blockIdx.x * (BSZ * 32) + (ibase + s * 4 + p) * 32 + o] = acc[p];
}

__global__ void reduce_kernel(const float* __restrict__ part, float* __restrict__ out) {
    int t = blockIdx.x * 256 + threadIdx.x;  // 0..16383
    float sum = 0.f;
#pragma unroll
    for (int jc = 0; jc < JSPLIT; ++jc) sum += part[jc * (BSZ * 32) + t];
    out[t] = sum;
}

extern "C" void kernel_launch(void* const* d_in, const int* in_sizes, int n_in,
                              void* d_out, int out_size, void* d_ws, size_t ws_size,
                              hipStream_t stream) {
    const float* x = (const float*)d_in[0];   // [512][2048]
    const float* w = (const float*)d_in[1];   // [2048][1024]
    float* out = (float*)d_out;               // [512][32]
    char* ws = (char*)d_ws;

    // ws layout (8MB total):
    //   [0,2MB)  x_bf  (dead after gemm) -> reused as partials by pairwise
    //   [2,6MB)  wt_bf (w transposed, bf16)
    //   [6,8MB)  h     (fp32, 512x1024)
    unsigned short* xb = (unsigned short*)(ws);
    unsigned short* wt = (unsigned short*)(ws + (size_t)(2u << 20));
    float* h           = (float*)(ws + (size_t)(6u << 20));
    float* part        = (float*)(ws);  // overlaps xb; gemm completes first (same stream)

    conv_x_kernel<<<1024, 256, 0, stream>>>(x, xb);
    conv_w_kernel<<<dim3(32, 64), dim3(32, 8), 0, stream>>>(w, wt);
    gemm_kernel<<<dim3(16, 8), 256, 0, stream>>>(xb, wt, h);
    pairwise_kernel<<<dim3(JSPLIT, 16), 256, 0, stream>>>(h, part);
    reduce_kernel<<<64, 256, 0, stream>>>(part, out);
}

// Round 2
// 100.188 us; speedup vs baseline: 1.2114x; 1.2114x over previous
//
#include <hip/hip_runtime.h>
#include <hip/hip_bf16.h>
#include <math.h>

#define BSZ 512
#define KDIM 2048
#define JSPLIT 32
#define JCHUNK (BSZ / JSPLIT)  // 16

typedef __bf16 bf16x8 __attribute__((ext_vector_type(8)));
typedef float floatx4 __attribute__((ext_vector_type(4)));

#define GLOBAL_AS __attribute__((address_space(1)))
#define LDS_AS __attribute__((address_space(3)))

__device__ __forceinline__ unsigned short f2bf(float f) {
    unsigned int u = __builtin_bit_cast(unsigned int, f);
    u += 0x7FFFu + ((u >> 16) & 1u);  // RNE
    return (unsigned short)(u >> 16);
}

__device__ __forceinline__ void async_lds16(const void* g, void* l) {
    __builtin_amdgcn_global_load_lds(
        (const GLOBAL_AS unsigned int*)g,
        (LDS_AS unsigned int*)(uintptr_t)(l), 16, 0, 0);
}

// Fused prep: blocks [0,512): x fp32->bf16 (8 elems/thr).
//             blocks [512,2560): w [2048][1024] -> wt [1024][2048] bf16 transposed.
__global__ __launch_bounds__(256) void prep_kernel(const float* __restrict__ x,
                                                   const float* __restrict__ w,
                                                   unsigned short* __restrict__ xb,
                                                   unsigned short* __restrict__ wt) {
    __shared__ unsigned short tile[32][33];
    const int b = blockIdx.x, t = threadIdx.x;
    if (b < 512) {
        int idx = (b * 256 + t) * 2;
#pragma unroll
        for (int r = 0; r < 2; ++r) {
            float4 v = ((const float4*)x)[idx + r];
            ushort4 o4;
            o4.x = f2bf(v.x); o4.y = f2bf(v.y); o4.z = f2bf(v.z); o4.w = f2bf(v.w);
            ((ushort4*)xb)[idx + r] = o4;
        }
    } else {
        const int bw = b - 512;
        const int n0 = (bw & 31) * 32, k0 = (bw >> 5) * 32;
        const int tx = t & 31, ty = t >> 5;  // 32 x 8
#pragma unroll
        for (int s = 0; s < 4; ++s) {
            int kk = ty + 8 * s;
            tile[kk][tx] = f2bf(w[(k0 + kk) * 1024 + n0 + tx]);
        }
        __syncthreads();
#pragma unroll
        for (int s = 0; s < 4; ++s) {
            int r = ty + 8 * s;
            wt[(n0 + r) * 2048 + k0 + tx] = tile[tx][r];
        }
    }
}

// h[m][n] = sum_k xb[m][k]*wt[n][k]. M=512,N=1024,K=2048.
// 32x32 block tile, BK=64, grid (32 n-tiles, 16 m-tiles) = 512 blocks (2/CU).
// global_load_lds width-16 staging; 4 waves as 2x2 of 16x16 wave tiles.
__global__ __launch_bounds__(256) void gemm_kernel(const unsigned short* __restrict__ xb,
                                                   const unsigned short* __restrict__ wt,
                                                   float* __restrict__ h) {
    // [ks][row][k&31] bf16, 4KB each. No padding (global_load_lds needs contiguity).
    __shared__ unsigned short As[2][32][32];
    __shared__ unsigned short Bs[2][32][32];
    const int t = threadIdx.x;
    const int m0 = blockIdx.y * 32, n0 = blockIdx.x * 32;
    const int w = t >> 6, l = t & 63, lf = l & 15, q = l >> 4;
    const int wm = (w >> 1) * 16, wn = (w & 1) * 16;

    // staging chunk c = t (16B): ks=t>>7, row=(t>>2)&31, k8=(t&3)*8
    const unsigned short* ga = xb + (size_t)(m0 + ((t >> 2) & 31)) * 2048 + (t >> 7) * 32 + (t & 3) * 8;
    const unsigned short* gb = wt + (size_t)(n0 + ((t >> 2) & 31)) * 2048 + (t >> 7) * 32 + (t & 3) * 8;
    void* la = (char*)&As[0][0][0] + t * 16;
    void* lb = (char*)&Bs[0][0][0] + t * 16;

    floatx4 acc = {0.f, 0.f, 0.f, 0.f};
    for (int k0 = 0; k0 < KDIM; k0 += 64) {
        __syncthreads();
        async_lds16(ga + k0, la);
        async_lds16(gb + k0, lb);
        __syncthreads();
#pragma unroll
        for (int ks = 0; ks < 2; ++ks) {
            bf16x8 a = *(const bf16x8*)&As[ks][wm + lf][q * 8];
            bf16x8 bvec = *(const bf16x8*)&Bs[ks][wn + lf][q * 8];
            acc = __builtin_amdgcn_mfma_f32_16x16x32_bf16(a, bvec, acc, 0, 0, 0);
        }
    }
    // C/D: col = lane&15, row = quad*4 + reg
#pragma unroll
    for (int r = 0; r < 4; ++r)
        h[(size_t)(m0 + wm + q * 4 + r) * 1024 + n0 + wn + lf] = acc[r];
}

// features[i][o] = sum_j exp(-sum_u |h[i][u*32+o] - h[j][u*32+o]|)
// grid (JSPLIT, 16); thread: o=t&31, s=t>>5; 4 i's in registers; atomicAdd epilogue.
__global__ __launch_bounds__(256) void pairwise_kernel(const float* __restrict__ h,
                                                       float* __restrict__ out) {
    __shared__ float4 buf[2][256];
    const int t = threadIdx.x;
    const int o = t & 31, s = t >> 5;
    const int ibase = blockIdx.y * 32;
    const int j0 = blockIdx.x * JCHUNK;

    float hi[4][32];
#pragma unroll
    for (int p = 0; p < 4; ++p) {
        const float* hrow = h + (ibase + s * 4 + p) * 1024 + o;
#pragma unroll
        for (int u = 0; u < 32; ++u) hi[p][u] = hrow[u * 32];
    }

    {
        const float* hj = h + j0 * 1024 + o;
        float4 v;
        v.x = hj[(4 * s + 0) * 32]; v.y = hj[(4 * s + 1) * 32];
        v.z = hj[(4 * s + 2) * 32]; v.w = hj[(4 * s + 3) * 32];
        buf[0][s * 32 + o] = v;
    }
    __syncthreads();

    float acc[4] = {0.f, 0.f, 0.f, 0.f};
    int cur = 0;
    for (int jj = 0; jj < JCHUNK; ++jj) {
        float4 nv;
        const bool has_next = (jj + 1 < JCHUNK);
        if (has_next) {
            const float* hj = h + (j0 + jj + 1) * 1024 + o;
            nv.x = hj[(4 * s + 0) * 32]; nv.y = hj[(4 * s + 1) * 32];
            nv.z = hj[(4 * s + 2) * 32]; nv.w = hj[(4 * s + 3) * 32];
        }
        float d0 = 0.f, d1 = 0.f, d2 = 0.f, d3 = 0.f;
#pragma unroll
        for (int g = 0; g < 8; ++g) {
            float4 hj4 = buf[cur][g * 32 + o];
            d0 += fabsf(hi[0][4*g+0] - hj4.x); d1 += fabsf(hi[1][4*g+0] - hj4.x);
            d2 += fabsf(hi[2][4*g+0] - hj4.x); d3 += fabsf(hi[3][4*g+0] - hj4.x);
            d0 += fabsf(hi[0][4*g+1] - hj4.y); d1 += fabsf(hi[1][4*g+1] - hj4.y);
            d2 += fabsf(hi[2][4*g+1] - hj4.y); d3 += fabsf(hi[3][4*g+1] - hj4.y);
            d0 += fabsf(hi[0][4*g+2] - hj4.z); d1 += fabsf(hi[1][4*g+2] - hj4.z);
            d2 += fabsf(hi[2][4*g+2] - hj4.z); d3 += fabsf(hi[3][4*g+2] - hj4.z);
            d0 += fabsf(hi[0][4*g+3] - hj4.w); d1 += fabsf(hi[1][4*g+3] - hj4.w);
            d2 += fabsf(hi[2][4*g+3] - hj4.w); d3 += fabsf(hi[3][4*g+3] - hj4.w);
        }
        acc[0] += __expf(-d0); acc[1] += __expf(-d1);
        acc[2] += __expf(-d2); acc[3] += __expf(-d3);
        if (has_next) buf[cur ^ 1][s * 32 + o] = nv;
        __syncthreads();
        cur ^= 1;
    }
#pragma unroll
    for (int p = 0; p < 4; ++p)
        atomicAdd(&out[(ibase + s * 4 + p) * 32 + o], acc[p]);
}

extern "C" void kernel_launch(void* const* d_in, const int* in_sizes, int n_in,
                              void* d_out, int out_size, void* d_ws, size_t ws_size,
                              hipStream_t stream) {
    const float* x = (const float*)d_in[0];   // [512][2048]
    const float* w = (const float*)d_in[1];   // [2048][1024]
    float* out = (float*)d_out;               // [512][32]
    char* ws = (char*)d_ws;

    // ws: [0,2MB) xb bf16 | [2,6MB) wt bf16 | [6,8MB) h fp32
    unsigned short* xb = (unsigned short*)(ws);
    unsigned short* wt = (unsigned short*)(ws + (size_t)(2u << 20));
    float* h           = (float*)(ws + (size_t)(6u << 20));

    hipMemsetAsync(out, 0, (size_t)out_size * sizeof(float), stream);
    prep_kernel<<<2560, 256, 0, stream>>>(x, w, xb, wt);
    gemm_kernel<<<dim3(32, 16), 256, 0, stream>>>(xb, wt, h);
    pairwise_kernel<<<dim3(JSPLIT, 16), 256, 0, stream>>>(h, out);
}